// Round 1
// baseline (824.722 us; speedup 1.0000x reference)
//
#include <hip/hip_runtime.h>
#include <hip/hip_bf16.h>

// Sizes (hard-coded from reference): B=32, T=512, D=64, H=64, S=4096, 4H=256, 2H=128
#define T_ 512

typedef __attribute__((ext_vector_type(8))) short short8;
typedef __attribute__((ext_vector_type(4))) float f32x4;

__device__ __forceinline__ float sigmoid_f(float x){
  x = fminf(fmaxf(x, -30.f), 30.f);
  return 1.f/(1.f + __expf(-x));
}
__device__ __forceinline__ float tanh_f(float x){
  x = fminf(fmaxf(x, -15.f), 15.f);
  float e = __expf(2.f*x);
  return (e - 1.f)/(e + 1.f);
}
__device__ __forceinline__ float gelu_f(float x){
  float u = 0.7978845608028654f*(x + 0.044715f*x*x*x);
  return 0.5f*x*(1.f + tanh_f(u));
}

// ---------------- Kernel 1: xg = enc @ Wx + bh (bias folded) ----------------
// enc [16384,64], Wx [64,256] -> xg [16384,256] fp32
__global__ __launch_bounds__(256) void k_xg(const float* __restrict__ enc,
                                            const float* __restrict__ Wx,
                                            const float* __restrict__ bh,
                                            float* __restrict__ xg)
{
  __shared__ __align__(16) float es[64*64];
  int j = threadIdx.x;
  int g = blockIdx.x;                     // 256 blocks, 64 rows each
  const float* encg = enc + (size_t)g*64*64;
  for (int idx = j; idx < 64*64; idx += 256) es[idx] = encg[idx];
  float wx[64];
#pragma unroll
  for (int k = 0; k < 64; ++k) wx[k] = Wx[k*256 + j];   // column j in regs
  float bj = bh[j];
  __syncthreads();
  float* xo = xg + (size_t)g*64*256;
  for (int r = 0; r < 64; ++r){
    const float4* e4 = (const float4*)(es + r*64);
    float z0 = bj, z1 = 0.f, z2 = 0.f, z3 = 0.f;
#pragma unroll
    for (int k4 = 0; k4 < 16; ++k4){
      float4 v = e4[k4];
      z0 = fmaf(v.x, wx[4*k4+0], z0);
      z1 = fmaf(v.y, wx[4*k4+1], z1);
      z2 = fmaf(v.z, wx[4*k4+2], z2);
      z3 = fmaf(v.w, wx[4*k4+3], z3);
    }
    xo[r*256 + j] = (z0+z1)+(z2+z3);
  }
}

// ---------------- Kernel 2: persistent LSTM, one WG per batch ----------------
// xg [B,T,256] (bh folded), Wh [64,256] -> hs [B,T,64] fp32
__global__ __launch_bounds__(256) void k_lstm(const float* __restrict__ xg,
                                              const float* __restrict__ Wh,
                                              float* __restrict__ hs)
{
  __shared__ __align__(16) float hsm[64];
  __shared__ float zsm[256];
  int j = threadIdx.x;                  // gate column 0..255 (i,f,g,o blocks of 64)
  int b = blockIdx.x;
  float wh[64];
#pragma unroll
  for (int k = 0; k < 64; ++k) wh[k] = Wh[k*256 + j];   // Wh[:,j] in regs
  int lane = j & 63, wave = j >> 6;
  int m = wave*16 + (lane & 15);        // update index owned by first 16 lanes of each wave
  bool upd = (lane < 16);
  float c = 0.f;
  if (j < 64) hsm[j] = 0.f;
  const float* xr = xg + (size_t)b*T_*256;
  float* ho = hs + (size_t)b*T_*64;
  float xnext = xr[j];                  // prefetch t=0
  __syncthreads();
  for (int t = 0; t < T_; ++t){
    float z0 = xnext, z1 = 0.f, z2 = 0.f, z3 = 0.f;
    if (t+1 < T_) xnext = xr[(size_t)(t+1)*256 + j];    // prefetch next step
    const float4* h4 = (const float4*)hsm;
#pragma unroll
    for (int k4 = 0; k4 < 16; ++k4){
      float4 v = h4[k4];                // broadcast read
      z0 = fmaf(v.x, wh[4*k4+0], z0);
      z1 = fmaf(v.y, wh[4*k4+1], z1);
      z2 = fmaf(v.z, wh[4*k4+2], z2);
      z3 = fmaf(v.w, wh[4*k4+3], z3);
    }
    zsm[j] = (z0+z1)+(z2+z3);
    __syncthreads();                    // z ready; all h reads done
    if (upd){
      float zi = zsm[m], zf = zsm[64+m], zg = zsm[128+m], zo = zsm[192+m];
      c = sigmoid_f(zf)*c + sigmoid_f(zi)*tanh_f(zg);
      float h = sigmoid_f(zo)*tanh_f(c);
      hsm[m] = h;
      ho[(size_t)t*64 + m] = h;
    }
    __syncthreads();                    // h ready for next step
  }
}

// ---------------- Kernel 3: fused MLP (LN+gelu twice), writes h2 as bf16 ----
// hs [16384,64] -> h2g [16384,128] bf16
__global__ __launch_bounds__(256) void k_mlp(const float* __restrict__ hs,
    const float* __restrict__ W1, const float* __restrict__ b1,
    const float* __restrict__ g1, const float* __restrict__ be1,
    const float* __restrict__ W2, const float* __restrict__ b2,
    const float* __restrict__ g2, const float* __restrict__ be2,
    __hip_bfloat16* __restrict__ h2g)
{
  __shared__ __align__(16) float xs[2][64];
  __shared__ __align__(16) float vs[2][128];
  __shared__ float red[2][2][2];
  int tid = threadIdx.x;
  int jj = tid & 127, rg = tid >> 7;    // output column, row-group (2 rows per pass)
  int lane = tid & 63;
  int whalf = (tid >> 6) & 1;           // which wave within the row-group
  float w1c[64], w2c[128];
#pragma unroll
  for (int k = 0; k < 64; ++k) w1c[k] = W1[k*128 + jj];
#pragma unroll
  for (int k = 0; k < 128; ++k) w2c[k] = W2[k*128 + jj];
  float b1j = b1[jj], g1j = g1[jj], be1j = be1[jj];
  float b2j = b2[jj], g2j = g2[jj], be2j = be2[jj];
  int base = blockIdx.x * 64;           // 256 blocks x 64 rows
  for (int p = 0; p < 32; ++p){
    int r = base + p*2 + rg;
    if (whalf == 0) xs[rg][lane] = hs[(size_t)r*64 + lane];
    __syncthreads();                                    // B1: xs ready
    float a0 = b1j, a1 = 0.f;
    const float4* x4 = (const float4*)xs[rg];
#pragma unroll
    for (int k4 = 0; k4 < 16; ++k4){
      float4 v = x4[k4];
      a0 = fmaf(v.x, w1c[4*k4+0], a0);
      a1 = fmaf(v.y, w1c[4*k4+1], a1);
      a0 = fmaf(v.z, w1c[4*k4+2], a0);
      a1 = fmaf(v.w, w1c[4*k4+3], a1);
    }
    float a = a0 + a1;
    float s1 = a, s2 = a*a;
#pragma unroll
    for (int off = 32; off > 0; off >>= 1){
      s1 += __shfl_xor(s1, off, 64);
      s2 += __shfl_xor(s2, off, 64);
    }
    if (lane == 0){ red[rg][whalf][0] = s1; red[rg][whalf][1] = s2; }
    __syncthreads();                                    // B2: red ready
    s1 = red[rg][0][0] + red[rg][1][0];
    s2 = red[rg][0][1] + red[rg][1][1];
    float mean = s1*(1.f/128.f);
    float var  = s2*(1.f/128.f) - mean*mean;
    float rstd = rsqrtf(var + 1e-6f);
    float y = gelu_f((a - mean)*rstd*g1j + be1j);
    vs[rg][jj] = y;
    __syncthreads();                                    // B3: vs ready (also orders red reuse)
    float c0 = b2j, c1 = 0.f;
    const float4* v4 = (const float4*)vs[rg];
#pragma unroll
    for (int k4 = 0; k4 < 32; ++k4){
      float4 v = v4[k4];
      c0 = fmaf(v.x, w2c[4*k4+0], c0);
      c1 = fmaf(v.y, w2c[4*k4+1], c1);
      c0 = fmaf(v.z, w2c[4*k4+2], c0);
      c1 = fmaf(v.w, w2c[4*k4+3], c1);
    }
    float cc = c0 + c1;
    float t1 = cc, t2 = cc*cc;
#pragma unroll
    for (int off = 32; off > 0; off >>= 1){
      t1 += __shfl_xor(t1, off, 64);
      t2 += __shfl_xor(t2, off, 64);
    }
    if (lane == 0){ red[rg][whalf][0] = t1; red[rg][whalf][1] = t2; }
    __syncthreads();                                    // B4: red2 ready
    t1 = red[rg][0][0] + red[rg][1][0];
    t2 = red[rg][0][1] + red[rg][1][1];
    mean = t1*(1.f/128.f);
    var  = t2*(1.f/128.f) - mean*mean;
    rstd = rsqrtf(var + 1e-6f);
    float z = gelu_f((cc - mean)*rstd*g2j + be2j);
    h2g[(size_t)r*128 + jj] = __float2bfloat16(z);
  }
}

// ---------------- Kernel 3.5: Wo fp32 [128,4096] -> WoT bf16 [4096,128] -----
__global__ __launch_bounds__(256) void k_wot(const float* __restrict__ Wo,
                                             __hip_bfloat16* __restrict__ WoT)
{
  __shared__ __hip_bfloat16 tl[64][130];   // pad to dodge write conflicts
  int tid = threadIdx.x;
  int n0 = blockIdx.x * 64;                // 64 blocks of 64 n-columns
  for (int idx = tid; idx < 64*128; idx += 256){
    int k = idx >> 6, nl = idx & 63;       // coalesced read of Wo row k
    tl[nl][k] = __float2bfloat16(Wo[(size_t)k*4096 + n0 + nl]);
  }
  __syncthreads();
  for (int idx = tid; idx < 64*128; idx += 256){
    int nl = idx >> 7, k = idx & 127;      // coalesced write of WoT row
    WoT[(size_t)(n0 + nl)*128 + k] = tl[nl][k];
  }
}

// ---------------- Kernel 4: out = h2 @ Wo + bo via bf16 MFMA ----------------
// h2g [16384,128] bf16, WoT [4096,128] bf16, out [16384,4096] fp32
__global__ __launch_bounds__(256) void k_out(const __hip_bfloat16* __restrict__ h2g,
                                             const __hip_bfloat16* __restrict__ WoT,
                                             const float* __restrict__ bo,
                                             float* __restrict__ out)
{
  int bid = blockIdx.x;                 // 16384 = 256 Mblk x 64 Nblk
  int Mb = bid >> 6, Nb = bid & 63;     // consecutive bids share the A panel
  int tid = threadIdx.x;
  int w = tid >> 6, l = tid & 63;
  int wm = w >> 1, wn = w & 1;          // 2x2 waves -> 64x64 block tile
  int m0 = Mb*64 + wm*32, n0 = Nb*64 + wn*32;
  int lr = l & 15, lk = (l >> 4)*8;     // fragment lane mapping (16x16x32)
  f32x4 acc00 = {0.f,0.f,0.f,0.f}, acc01 = {0.f,0.f,0.f,0.f};
  f32x4 acc10 = {0.f,0.f,0.f,0.f}, acc11 = {0.f,0.f,0.f,0.f};
  const short* A  = (const short*)h2g;
  const short* Bp = (const short*)WoT;
#pragma unroll
  for (int kk = 0; kk < 4; ++kk){
    int ko = kk*32 + lk;
    short8 a0 = *(const short8*)(A  + (size_t)(m0      + lr)*128 + ko);
    short8 a1 = *(const short8*)(A  + (size_t)(m0 + 16 + lr)*128 + ko);
    short8 b0 = *(const short8*)(Bp + (size_t)(n0      + lr)*128 + ko);
    short8 b1 = *(const short8*)(Bp + (size_t)(n0 + 16 + lr)*128 + ko);
    acc00 = __builtin_amdgcn_mfma_f32_16x16x32_bf16(a0, b0, acc00, 0, 0, 0);
    acc01 = __builtin_amdgcn_mfma_f32_16x16x32_bf16(a0, b1, acc01, 0, 0, 0);
    acc10 = __builtin_amdgcn_mfma_f32_16x16x32_bf16(a1, b0, acc10, 0, 0, 0);
    acc11 = __builtin_amdgcn_mfma_f32_16x16x32_bf16(a1, b1, acc11, 0, 0, 0);
  }
  int r0 = (l >> 4)*4;                  // C/D: col=lane&15, row=(lane>>4)*4+reg
  float bias0 = bo[n0 + lr];
  float bias1 = bo[n0 + 16 + lr];
#pragma unroll
  for (int rr = 0; rr < 4; ++rr){
    out[(size_t)(m0      + r0 + rr)*4096 + n0      + lr] = acc00[rr] + bias0;
    out[(size_t)(m0      + r0 + rr)*4096 + n0 + 16 + lr] = acc01[rr] + bias1;
    out[(size_t)(m0 + 16 + r0 + rr)*4096 + n0      + lr] = acc10[rr] + bias0;
    out[(size_t)(m0 + 16 + r0 + rr)*4096 + n0 + 16 + lr] = acc11[rr] + bias1;
  }
}

extern "C" void kernel_launch(void* const* d_in, const int* in_sizes, int n_in,
                              void* d_out, int out_size, void* d_ws, size_t ws_size,
                              hipStream_t stream)
{
  const float* enc = (const float*)d_in[0];
  const float* Wx  = (const float*)d_in[1];
  const float* Wh  = (const float*)d_in[2];
  const float* bh  = (const float*)d_in[3];
  const float* W1  = (const float*)d_in[4];
  const float* b1  = (const float*)d_in[5];
  const float* g1  = (const float*)d_in[6];
  const float* be1 = (const float*)d_in[7];
  const float* W2  = (const float*)d_in[8];
  const float* b2  = (const float*)d_in[9];
  const float* g2  = (const float*)d_in[10];
  const float* be2 = (const float*)d_in[11];
  const float* Wo  = (const float*)d_in[12];
  const float* bo  = (const float*)d_in[13];
  float* out = (float*)d_out;

  const size_t xg_bytes = (size_t)16384*256*4;   // 16 MiB
  const size_t hs_bytes = (size_t)16384*64*4;    //  4 MiB
  const size_t h2_bytes = (size_t)16384*128*2;   //  4 MiB (bf16)
  const size_t wt_bytes = (size_t)4096*128*2;    //  1 MiB (bf16)
  char* ws = (char*)d_ws;
  float *xg, *hs; __hip_bfloat16 *h2g, *WoT;
  if (ws_size >= xg_bytes + hs_bytes + h2_bytes + wt_bytes){
    xg  = (float*)ws;
    hs  = (float*)(ws + xg_bytes);
    h2g = (__hip_bfloat16*)(ws + xg_bytes + hs_bytes);
    WoT = (__hip_bfloat16*)(ws + xg_bytes + hs_bytes + h2_bytes);
  } else {
    // scratch-starved fallback: xg/hs live in d_out (dead before k_out overwrites it)
    xg  = (float*)d_out;
    hs  = (float*)((char*)d_out + xg_bytes);
    h2g = (__hip_bfloat16*)ws;
    WoT = (__hip_bfloat16*)(ws + h2_bytes);
  }

  k_xg  <<<256,   256, 0, stream>>>(enc, Wx, bh, xg);
  k_wot <<<64,    256, 0, stream>>>(Wo, WoT);
  k_lstm<<<32,    256, 0, stream>>>(xg, Wh, hs);
  k_mlp <<<256,   256, 0, stream>>>(hs, W1, b1, g1, be1, W2, b2, g2, be2, h2g);
  k_out <<<16384, 256, 0, stream>>>(h2g, WoT, bo, out);
}

// Round 2
// 511.290 us; speedup vs baseline: 1.6130x; 1.6130x over previous
//
#include <hip/hip_runtime.h>
#include <hip/hip_bf16.h>

// Sizes (hard-coded from reference): B=32, T=512, D=64, H=64, S=4096, 4H=256, 2H=128
#define T_ 512

typedef __attribute__((ext_vector_type(8))) short short8;
typedef __attribute__((ext_vector_type(4))) float f32x4;

__device__ __forceinline__ float fast_rcp(float x){ return __builtin_amdgcn_rcpf(x); }
__device__ __forceinline__ float sigmoid_f(float x){
  x = fminf(fmaxf(x, -30.f), 30.f);
  return fast_rcp(1.f + __expf(-x));          // v_exp + v_rcp, no fdiv sequence
}
__device__ __forceinline__ float tanh_f(float x){
  x = fminf(fmaxf(x, -15.f), 15.f);
  return fmaf(2.f, fast_rcp(1.f + __expf(-2.f*x)), -1.f);   // 2*sigmoid(2x)-1
}
__device__ __forceinline__ float gelu_f(float x){
  float u = 0.7978845608028654f*(x + 0.044715f*x*x*x);
  return 0.5f*x*(1.f + tanh_f(u));
}

// ---------------- Kernel 1: xg = enc @ Wx + bh (bias folded) ----------------
// enc [16384,64], Wx [64,256] -> xg [16384,256] fp32
__global__ __launch_bounds__(256) void k_xg(const float* __restrict__ enc,
                                            const float* __restrict__ Wx,
                                            const float* __restrict__ bh,
                                            float* __restrict__ xg)
{
  __shared__ __align__(16) float es[64*64];
  int j = threadIdx.x;
  int g = blockIdx.x;                     // 256 blocks, 64 rows each
  const float* encg = enc + (size_t)g*64*64;
  for (int idx = j; idx < 64*64; idx += 256) es[idx] = encg[idx];
  float wx[64];
#pragma unroll
  for (int k = 0; k < 64; ++k) wx[k] = Wx[k*256 + j];   // column j in regs
  float bj = bh[j];
  __syncthreads();
  float* xo = xg + (size_t)g*64*256;
  for (int r = 0; r < 64; ++r){
    const float4* e4 = (const float4*)(es + r*64);
    float z0 = bj, z1 = 0.f, z2 = 0.f, z3 = 0.f;
#pragma unroll
    for (int k4 = 0; k4 < 16; ++k4){
      float4 v = e4[k4];
      z0 = fmaf(v.x, wx[4*k4+0], z0);
      z1 = fmaf(v.y, wx[4*k4+1], z1);
      z2 = fmaf(v.z, wx[4*k4+2], z2);
      z3 = fmaf(v.w, wx[4*k4+3], z3);
    }
    xo[r*256 + j] = (z0+z1)+(z2+z3);
  }
}

// ---------------- Kernel 2: persistent LSTM, one WG per batch ----------------
// Wave w owns units [16w,16w+16); lane l computes gate g=(l>>4) of unit m=16w+(l&15).
// Gate exchange is intra-wave (3x shfl_xor), h broadcast via double-buffered LDS
// -> exactly ONE barrier and ONE LDS round trip per timestep, no fdiv.
__global__ __launch_bounds__(256) void k_lstm(const float* __restrict__ xg,
                                              const float* __restrict__ Wh,
                                              float* __restrict__ hs)
{
  __shared__ __align__(16) float hb[2][64];
  int tid = threadIdx.x;
  int w = tid >> 6, l = tid & 63;
  int m = w*16 + (l & 15);              // unit owned (update lanes l<16)
  int g = l >> 4;                       // gate index 0..3 (i,f,g,o)
  int j = g*64 + m;                     // column of Wh/xg this thread computes
  int b = blockIdx.x;
  float wh[64];
#pragma unroll
  for (int k = 0; k < 64; ++k) wh[k] = Wh[k*256 + j];   // Wh[:,j] in regs
  bool upd = (l < 16);
  float c = 0.f;
  if (tid < 64) hb[0][tid] = 0.f;
  const float* xr = xg + (size_t)b*T_*256;
  float* ho = hs + (size_t)b*T_*64;
  float xnext = xr[j];                  // prefetch t=0
  __syncthreads();
  for (int t = 0; t < T_; ++t){
    const float4* h4 = (const float4*)hb[t & 1];
    float z0 = xnext, z1 = 0.f, z2 = 0.f, z3 = 0.f;
    if (t+1 < T_) xnext = xr[(size_t)(t+1)*256 + j];    // prefetch next step
#pragma unroll
    for (int k4 = 0; k4 < 16; ++k4){
      float4 v = h4[k4];                // broadcast read (conflict-free)
      z0 = fmaf(v.x, wh[4*k4+0], z0);
      z1 = fmaf(v.y, wh[4*k4+1], z1);
      z2 = fmaf(v.z, wh[4*k4+2], z2);
      z3 = fmaf(v.w, wh[4*k4+3], z3);
    }
    float z = (z0+z1)+(z2+z3);
    float zB = __shfl_xor(z, 16);       // lane<16: f-gate
    float zC = __shfl_xor(z, 32);       // lane<16: g-gate
    float zD = __shfl_xor(z, 48);       // lane<16: o-gate
    if (upd){
      c = sigmoid_f(zB)*c + sigmoid_f(z)*tanh_f(zC);
      float h = sigmoid_f(zD)*tanh_f(c);
      hb[(t+1) & 1][m] = h;
      ho[(size_t)t*64 + m] = h;
    }
    __syncthreads();                    // write buf ready; read buf retired
  }
}

// ---------------- Kernel 3: fused MLP (LN+gelu twice), writes h2 as bf16 ----
// hs [16384,64] -> h2g [16384,128] bf16
__global__ __launch_bounds__(256) void k_mlp(const float* __restrict__ hs,
    const float* __restrict__ W1, const float* __restrict__ b1,
    const float* __restrict__ g1, const float* __restrict__ be1,
    const float* __restrict__ W2, const float* __restrict__ b2,
    const float* __restrict__ g2, const float* __restrict__ be2,
    __hip_bfloat16* __restrict__ h2g)
{
  __shared__ __align__(16) float xs[2][64];
  __shared__ __align__(16) float vs[2][128];
  __shared__ float red[2][2][2];
  int tid = threadIdx.x;
  int jj = tid & 127, rg = tid >> 7;    // output column, row-group (2 rows per pass)
  int lane = tid & 63;
  int whalf = (tid >> 6) & 1;           // which wave within the row-group
  float w1c[64], w2c[128];
#pragma unroll
  for (int k = 0; k < 64; ++k) w1c[k] = W1[k*128 + jj];
#pragma unroll
  for (int k = 0; k < 128; ++k) w2c[k] = W2[k*128 + jj];
  float b1j = b1[jj], g1j = g1[jj], be1j = be1[jj];
  float b2j = b2[jj], g2j = g2[jj], be2j = be2[jj];
  int base = blockIdx.x * 64;           // 256 blocks x 64 rows
  for (int p = 0; p < 32; ++p){
    int r = base + p*2 + rg;
    if (whalf == 0) xs[rg][lane] = hs[(size_t)r*64 + lane];
    __syncthreads();                                    // B1: xs ready
    float a0 = b1j, a1 = 0.f;
    const float4* x4 = (const float4*)xs[rg];
#pragma unroll
    for (int k4 = 0; k4 < 16; ++k4){
      float4 v = x4[k4];
      a0 = fmaf(v.x, w1c[4*k4+0], a0);
      a1 = fmaf(v.y, w1c[4*k4+1], a1);
      a0 = fmaf(v.z, w1c[4*k4+2], a0);
      a1 = fmaf(v.w, w1c[4*k4+3], a1);
    }
    float a = a0 + a1;
    float s1 = a, s2 = a*a;
#pragma unroll
    for (int off = 32; off > 0; off >>= 1){
      s1 += __shfl_xor(s1, off, 64);
      s2 += __shfl_xor(s2, off, 64);
    }
    if (lane == 0){ red[rg][whalf][0] = s1; red[rg][whalf][1] = s2; }
    __syncthreads();                                    // B2: red ready
    s1 = red[rg][0][0] + red[rg][1][0];
    s2 = red[rg][0][1] + red[rg][1][1];
    float mean = s1*(1.f/128.f);
    float var  = s2*(1.f/128.f) - mean*mean;
    float rstd = rsqrtf(var + 1e-6f);
    float y = gelu_f((a - mean)*rstd*g1j + be1j);
    vs[rg][jj] = y;
    __syncthreads();                                    // B3: vs ready (also orders red reuse)
    float c0 = b2j, c1 = 0.f;
    const float4* v4 = (const float4*)vs[rg];
#pragma unroll
    for (int k4 = 0; k4 < 32; ++k4){
      float4 v = v4[k4];
      c0 = fmaf(v.x, w2c[4*k4+0], c0);
      c1 = fmaf(v.y, w2c[4*k4+1], c1);
      c0 = fmaf(v.z, w2c[4*k4+2], c0);
      c1 = fmaf(v.w, w2c[4*k4+3], c1);
    }
    float cc = c0 + c1;
    float t1 = cc, t2 = cc*cc;
#pragma unroll
    for (int off = 32; off > 0; off >>= 1){
      t1 += __shfl_xor(t1, off, 64);
      t2 += __shfl_xor(t2, off, 64);
    }
    if (lane == 0){ red[rg][whalf][0] = t1; red[rg][whalf][1] = t2; }
    __syncthreads();                                    // B4: red2 ready
    t1 = red[rg][0][0] + red[rg][1][0];
    t2 = red[rg][0][1] + red[rg][1][1];
    mean = t1*(1.f/128.f);
    var  = t2*(1.f/128.f) - mean*mean;
    rstd = rsqrtf(var + 1e-6f);
    float z = gelu_f((cc - mean)*rstd*g2j + be2j);
    h2g[(size_t)r*128 + jj] = __float2bfloat16(z);
  }
}

// ---------------- Kernel 3.5: Wo fp32 [128,4096] -> WoT bf16 [4096,128] -----
__global__ __launch_bounds__(256) void k_wot(const float* __restrict__ Wo,
                                             __hip_bfloat16* __restrict__ WoT)
{
  __shared__ __hip_bfloat16 tl[64][130];   // pad to dodge write conflicts
  int tid = threadIdx.x;
  int n0 = blockIdx.x * 64;                // 64 blocks of 64 n-columns
  for (int idx = tid; idx < 64*128; idx += 256){
    int k = idx >> 6, nl = idx & 63;       // coalesced read of Wo row k
    tl[nl][k] = __float2bfloat16(Wo[(size_t)k*4096 + n0 + nl]);
  }
  __syncthreads();
  for (int idx = tid; idx < 64*128; idx += 256){
    int nl = idx >> 7, k = idx & 127;      // coalesced write of WoT row
    WoT[(size_t)(n0 + nl)*128 + k] = tl[nl][k];
  }
}

// ---------------- Kernel 4: out = h2 @ Wo + bo via bf16 MFMA ----------------
// Operand roles swapped (A=WoT n-rows, B=h2g m-rows) so D's reg axis runs
// along n (contiguous in out) -> float4 nontemporal stores.
// h2g [16384,128] bf16, WoT [4096,128] bf16, out [16384,4096] fp32
__global__ __launch_bounds__(256) void k_out(const __hip_bfloat16* __restrict__ h2g,
                                             const __hip_bfloat16* __restrict__ WoT,
                                             const float* __restrict__ bo,
                                             float* __restrict__ out)
{
  int bid = blockIdx.x;                 // 16384 = 256 Mblk x 64 Nblk
  int Mb = bid >> 6, Nb = bid & 63;     // consecutive bids share the A panel
  int tid = threadIdx.x;
  int w = tid >> 6, l = tid & 63;
  int wn = w >> 1, wm = w & 1;          // 2x2 waves -> 64(m) x 64(n) block tile
  int n0 = Nb*64 + wn*32, m0 = Mb*64 + wm*32;
  int lr = l & 15, lk = (l >> 4)*8;     // fragment lane mapping (16x16x32)
  f32x4 acc00 = {0.f,0.f,0.f,0.f}, acc01 = {0.f,0.f,0.f,0.f};
  f32x4 acc10 = {0.f,0.f,0.f,0.f}, acc11 = {0.f,0.f,0.f,0.f};
  const short* A  = (const short*)WoT;  // A rows indexed by n
  const short* Bp = (const short*)h2g;  // B rows indexed by m
#pragma unroll
  for (int kk = 0; kk < 4; ++kk){
    int ko = kk*32 + lk;
    short8 a0 = *(const short8*)(A  + (size_t)(n0      + lr)*128 + ko);
    short8 a1 = *(const short8*)(A  + (size_t)(n0 + 16 + lr)*128 + ko);
    short8 b0 = *(const short8*)(Bp + (size_t)(m0      + lr)*128 + ko);
    short8 b1 = *(const short8*)(Bp + (size_t)(m0 + 16 + lr)*128 + ko);
    acc00 = __builtin_amdgcn_mfma_f32_16x16x32_bf16(a0, b0, acc00, 0, 0, 0);  // n0   , m0
    acc01 = __builtin_amdgcn_mfma_f32_16x16x32_bf16(a0, b1, acc01, 0, 0, 0);  // n0   , m0+16
    acc10 = __builtin_amdgcn_mfma_f32_16x16x32_bf16(a1, b0, acc10, 0, 0, 0);  // n0+16, m0
    acc11 = __builtin_amdgcn_mfma_f32_16x16x32_bf16(a1, b1, acc11, 0, 0, 0);  // n0+16, m0+16
  }
  // D layout: col(lane&15) = m index, row((lane>>4)*4+reg) = n index (contiguous!)
  int nb_ = (l >> 4)*4;
  f32x4 bia0 = *(const f32x4*)(bo + n0 + nb_);
  f32x4 bia1 = *(const f32x4*)(bo + n0 + 16 + nb_);
  size_t row0 = (size_t)(m0 + lr)*4096;
  size_t row1 = (size_t)(m0 + 16 + lr)*4096;
  __builtin_nontemporal_store(acc00 + bia0, (f32x4*)(out + row0 + n0 + nb_));
  __builtin_nontemporal_store(acc10 + bia1, (f32x4*)(out + row0 + n0 + 16 + nb_));
  __builtin_nontemporal_store(acc01 + bia0, (f32x4*)(out + row1 + n0 + nb_));
  __builtin_nontemporal_store(acc11 + bia1, (f32x4*)(out + row1 + n0 + 16 + nb_));
}

extern "C" void kernel_launch(void* const* d_in, const int* in_sizes, int n_in,
                              void* d_out, int out_size, void* d_ws, size_t ws_size,
                              hipStream_t stream)
{
  const float* enc = (const float*)d_in[0];
  const float* Wx  = (const float*)d_in[1];
  const float* Wh  = (const float*)d_in[2];
  const float* bh  = (const float*)d_in[3];
  const float* W1  = (const float*)d_in[4];
  const float* b1  = (const float*)d_in[5];
  const float* g1  = (const float*)d_in[6];
  const float* be1 = (const float*)d_in[7];
  const float* W2  = (const float*)d_in[8];
  const float* b2  = (const float*)d_in[9];
  const float* g2  = (const float*)d_in[10];
  const float* be2 = (const float*)d_in[11];
  const float* Wo  = (const float*)d_in[12];
  const float* bo  = (const float*)d_in[13];
  float* out = (float*)d_out;

  const size_t xg_bytes = (size_t)16384*256*4;   // 16 MiB
  const size_t hs_bytes = (size_t)16384*64*4;    //  4 MiB
  const size_t h2_bytes = (size_t)16384*128*2;   //  4 MiB (bf16)
  const size_t wt_bytes = (size_t)4096*128*2;    //  1 MiB (bf16)
  char* ws = (char*)d_ws;
  float *xg, *hs; __hip_bfloat16 *h2g, *WoT;
  if (ws_size >= xg_bytes + hs_bytes + h2_bytes + wt_bytes){
    xg  = (float*)ws;
    hs  = (float*)(ws + xg_bytes);
    h2g = (__hip_bfloat16*)(ws + xg_bytes + hs_bytes);
    WoT = (__hip_bfloat16*)(ws + xg_bytes + hs_bytes + h2_bytes);
  } else {
    // scratch-starved fallback: xg/hs live in d_out (dead before k_out overwrites it)
    xg  = (float*)d_out;
    hs  = (float*)((char*)d_out + xg_bytes);
    h2g = (__hip_bfloat16*)ws;
    WoT = (__hip_bfloat16*)(ws + h2_bytes);
  }

  k_xg  <<<256,   256, 0, stream>>>(enc, Wx, bh, xg);
  k_wot <<<64,    256, 0, stream>>>(Wo, WoT);
  k_lstm<<<32,    256, 0, stream>>>(xg, Wh, hs);
  k_mlp <<<256,   256, 0, stream>>>(hs, W1, b1, g1, be1, W2, b2, g2, be2, h2g);
  k_out <<<16384, 256, 0, stream>>>(h2g, WoT, bo, out);
}

// Round 3
// 471.424 us; speedup vs baseline: 1.7494x; 1.0846x over previous
//
#include <hip/hip_runtime.h>
#include <hip/hip_bf16.h>

// Sizes (hard-coded from reference): B=32, T=512, D=64, H=64, S=4096, 4H=256, 2H=128
#define T_ 512

typedef __attribute__((ext_vector_type(8))) short short8;
typedef __attribute__((ext_vector_type(4))) float f32x4;

__device__ __forceinline__ float fast_rcp(float x){ return __builtin_amdgcn_rcpf(x); }
// Clamp-free: exp->inf saturates cleanly through rcp (sigmoid->0/1, tanh->+-1)
__device__ __forceinline__ float sigmoid_f(float x){
  return fast_rcp(1.f + __expf(-x));
}
__device__ __forceinline__ float tanh_f(float x){
  return fmaf(2.f, fast_rcp(1.f + __expf(-2.f*x)), -1.f);
}
__device__ __forceinline__ float gelu_f(float x){
  float u = 0.7978845608028654f*(x + 0.044715f*x*x*x);
  return 0.5f*x*(1.f + tanh_f(u));
}

// ---------------- Kernel 1: xg = enc @ Wx + bh (bias folded) ----------------
// enc [16384,64], Wx [64,256] -> xg [16384,256] fp32
__global__ __launch_bounds__(256) void k_xg(const float* __restrict__ enc,
                                            const float* __restrict__ Wx,
                                            const float* __restrict__ bh,
                                            float* __restrict__ xg)
{
  __shared__ __align__(16) float es[64*64];
  int j = threadIdx.x;
  int g = blockIdx.x;                     // 256 blocks, 64 rows each
  const float* encg = enc + (size_t)g*64*64;
  for (int idx = j; idx < 64*64; idx += 256) es[idx] = encg[idx];
  float wx[64];
#pragma unroll
  for (int k = 0; k < 64; ++k) wx[k] = Wx[k*256 + j];   // column j in regs
  float bj = bh[j];
  __syncthreads();
  float* xo = xg + (size_t)g*64*256;
  for (int r = 0; r < 64; ++r){
    const float4* e4 = (const float4*)(es + r*64);
    float z0 = bj, z1 = 0.f, z2 = 0.f, z3 = 0.f;
#pragma unroll
    for (int k4 = 0; k4 < 16; ++k4){
      float4 v = e4[k4];
      z0 = fmaf(v.x, wx[4*k4+0], z0);
      z1 = fmaf(v.y, wx[4*k4+1], z1);
      z2 = fmaf(v.z, wx[4*k4+2], z2);
      z3 = fmaf(v.w, wx[4*k4+3], z3);
    }
    xo[r*256 + j] = (z0+z1)+(z2+z3);
  }
}

// ---------------- Kernel 2: persistent LSTM, one WG per batch ----------------
// Wave w owns units [16w,16w+16); lane l computes gate g=(l>>4) of unit m=16w+(l&15).
// Gate exchange intra-wave (3x shfl_xor); h double-buffered in LDS (1 barrier/step).
// xg prefetched FOUR steps deep so ~900cy HBM latency hides under 4 step-chains.
__global__ __launch_bounds__(256) void k_lstm(const float* __restrict__ xg,
                                              const float* __restrict__ Wh,
                                              float* __restrict__ hs)
{
  __shared__ __align__(16) float hb[2][64];
  int tid = threadIdx.x;
  int w = tid >> 6, l = tid & 63;
  int m = w*16 + (l & 15);              // unit owned (update lanes l<16)
  int g = l >> 4;                       // gate index 0..3 (i,f,g,o)
  int j = g*64 + m;                     // column of Wh/xg this thread computes
  int b = blockIdx.x;
  float wh[64];
#pragma unroll
  for (int k = 0; k < 64; ++k) wh[k] = Wh[k*256 + j];   // Wh[:,j] in regs
  bool upd = (l < 16);
  float c = 0.f;
  if (tid < 64) hb[0][tid] = 0.f;
  const float* xr = xg + (size_t)b*T_*256;
  float* ho = hs + (size_t)b*T_*64;
  float xn0 = xr[j];                    // 4-deep prefetch pipeline
  float xn1 = xr[256 + j];
  float xn2 = xr[512 + j];
  float xn3 = xr[768 + j];
  __syncthreads();

#define LSTM_STEP(tt, xn)                                                     \
  {                                                                           \
    const float4* h4 = (const float4*)hb[(tt) & 1];                           \
    float z0 = (xn), z1 = 0.f, z2 = 0.f, z3 = 0.f;                            \
    if ((tt) + 4 < T_) (xn) = xr[(size_t)((tt) + 4)*256 + j];                 \
    _Pragma("unroll")                                                         \
    for (int k4 = 0; k4 < 16; ++k4){                                          \
      float4 v = h4[k4];                                                      \
      z0 = fmaf(v.x, wh[4*k4+0], z0);                                         \
      z1 = fmaf(v.y, wh[4*k4+1], z1);                                         \
      z2 = fmaf(v.z, wh[4*k4+2], z2);                                         \
      z3 = fmaf(v.w, wh[4*k4+3], z3);                                         \
    }                                                                         \
    float z = (z0+z1)+(z2+z3);                                                \
    float zB = __shfl_xor(z, 16);       /* lane<16: f-gate */                 \
    float zC = __shfl_xor(z, 32);       /* lane<16: g-gate */                 \
    float zD = __shfl_xor(z, 48);       /* lane<16: o-gate */                 \
    if (upd){                                                                 \
      c = sigmoid_f(zB)*c + sigmoid_f(z)*tanh_f(zC);                          \
      float h = sigmoid_f(zD)*tanh_f(c);                                      \
      hb[((tt)+1) & 1][m] = h;                                                \
      ho[(size_t)(tt)*64 + m] = h;                                            \
    }                                                                         \
    __syncthreads();                                                          \
  }

  for (int t = 0; t < T_; t += 4){
    LSTM_STEP(t,   xn0);
    LSTM_STEP(t+1, xn1);
    LSTM_STEP(t+2, xn2);
    LSTM_STEP(t+3, xn3);
  }
#undef LSTM_STEP
}

// ---------------- Kernel 3: fused MLP (LN+gelu twice), writes h2 as bf16 ----
// hs [16384,64] -> h2g [16384,128] bf16
__global__ __launch_bounds__(256) void k_mlp(const float* __restrict__ hs,
    const float* __restrict__ W1, const float* __restrict__ b1,
    const float* __restrict__ g1, const float* __restrict__ be1,
    const float* __restrict__ W2, const float* __restrict__ b2,
    const float* __restrict__ g2, const float* __restrict__ be2,
    __hip_bfloat16* __restrict__ h2g)
{
  __shared__ __align__(16) float xs[2][64];
  __shared__ __align__(16) float vs[2][128];
  __shared__ float red[2][2][2];
  int tid = threadIdx.x;
  int jj = tid & 127, rg = tid >> 7;    // output column, row-group (2 rows per pass)
  int lane = tid & 63;
  int whalf = (tid >> 6) & 1;           // which wave within the row-group
  float w1c[64], w2c[128];
#pragma unroll
  for (int k = 0; k < 64; ++k) w1c[k] = W1[k*128 + jj];
#pragma unroll
  for (int k = 0; k < 128; ++k) w2c[k] = W2[k*128 + jj];
  float b1j = b1[jj], g1j = g1[jj], be1j = be1[jj];
  float b2j = b2[jj], g2j = g2[jj], be2j = be2[jj];
  int base = blockIdx.x * 64;           // 256 blocks x 64 rows
  for (int p = 0; p < 32; ++p){
    int r = base + p*2 + rg;
    if (whalf == 0) xs[rg][lane] = hs[(size_t)r*64 + lane];
    __syncthreads();                                    // B1: xs ready
    float a0 = b1j, a1 = 0.f;
    const float4* x4 = (const float4*)xs[rg];
#pragma unroll
    for (int k4 = 0; k4 < 16; ++k4){
      float4 v = x4[k4];
      a0 = fmaf(v.x, w1c[4*k4+0], a0);
      a1 = fmaf(v.y, w1c[4*k4+1], a1);
      a0 = fmaf(v.z, w1c[4*k4+2], a0);
      a1 = fmaf(v.w, w1c[4*k4+3], a1);
    }
    float a = a0 + a1;
    float s1 = a, s2 = a*a;
#pragma unroll
    for (int off = 32; off > 0; off >>= 1){
      s1 += __shfl_xor(s1, off, 64);
      s2 += __shfl_xor(s2, off, 64);
    }
    if (lane == 0){ red[rg][whalf][0] = s1; red[rg][whalf][1] = s2; }
    __syncthreads();                                    // B2: red ready
    s1 = red[rg][0][0] + red[rg][1][0];
    s2 = red[rg][0][1] + red[rg][1][1];
    float mean = s1*(1.f/128.f);
    float var  = s2*(1.f/128.f) - mean*mean;
    float rstd = rsqrtf(var + 1e-6f);
    float y = gelu_f((a - mean)*rstd*g1j + be1j);
    vs[rg][jj] = y;
    __syncthreads();                                    // B3: vs ready (also orders red reuse)
    float c0 = b2j, c1 = 0.f;
    const float4* v4 = (const float4*)vs[rg];
#pragma unroll
    for (int k4 = 0; k4 < 32; ++k4){
      float4 v = v4[k4];
      c0 = fmaf(v.x, w2c[4*k4+0], c0);
      c1 = fmaf(v.y, w2c[4*k4+1], c1);
      c0 = fmaf(v.z, w2c[4*k4+2], c0);
      c1 = fmaf(v.w, w2c[4*k4+3], c1);
    }
    float cc = c0 + c1;
    float t1 = cc, t2 = cc*cc;
#pragma unroll
    for (int off = 32; off > 0; off >>= 1){
      t1 += __shfl_xor(t1, off, 64);
      t2 += __shfl_xor(t2, off, 64);
    }
    if (lane == 0){ red[rg][whalf][0] = t1; red[rg][whalf][1] = t2; }
    __syncthreads();                                    // B4: red2 ready
    t1 = red[rg][0][0] + red[rg][1][0];
    t2 = red[rg][0][1] + red[rg][1][1];
    mean = t1*(1.f/128.f);
    var  = t2*(1.f/128.f) - mean*mean;
    rstd = rsqrtf(var + 1e-6f);
    float z = gelu_f((cc - mean)*rstd*g2j + be2j);
    h2g[(size_t)r*128 + jj] = __float2bfloat16(z);
  }
}

// ---------------- Kernel 3.5: Wo fp32 [128,4096] -> WoT bf16 [4096,128] -----
__global__ __launch_bounds__(256) void k_wot(const float* __restrict__ Wo,
                                             __hip_bfloat16* __restrict__ WoT)
{
  __shared__ __hip_bfloat16 tl[64][130];   // pad to dodge write conflicts
  int tid = threadIdx.x;
  int n0 = blockIdx.x * 64;                // 64 blocks of 64 n-columns
  for (int idx = tid; idx < 64*128; idx += 256){
    int k = idx >> 6, nl = idx & 63;       // coalesced read of Wo row k
    tl[nl][k] = __float2bfloat16(Wo[(size_t)k*4096 + n0 + nl]);
  }
  __syncthreads();
  for (int idx = tid; idx < 64*128; idx += 256){
    int nl = idx >> 7, k = idx & 127;      // coalesced write of WoT row
    WoT[(size_t)(n0 + nl)*128 + k] = tl[nl][k];
  }
}

// ---------------- Kernel 4: out = h2 @ Wo + bo via bf16 MFMA ----------------
// 128x128 block tile (4 waves 2x2, 4x4 fragments each) -> halves panel
// re-reads vs 64x64 and amortizes address calc over 64 MFMA/wave.
// A=WoT (rows=n), B=h2g (rows=m) so D's reg axis runs along n -> float4 stores.
__global__ __launch_bounds__(256) void k_out(const __hip_bfloat16* __restrict__ h2g,
                                             const __hip_bfloat16* __restrict__ WoT,
                                             const float* __restrict__ bo,
                                             float* __restrict__ out)
{
  int bid = blockIdx.x;                 // 4096 = 128 Mb x 32 Nb (Nb inner: share m-panel)
  int Mb = bid >> 5, Nb = bid & 31;
  int tid = threadIdx.x;
  int w = tid >> 6, l = tid & 63;
  int wm = w >> 1, wn = w & 1;          // 2x2 waves -> 128(m) x 128(n)
  int m0 = Mb*128 + wm*64, n0 = Nb*128 + wn*64;
  int lr = l & 15, lk = (l >> 4)*8;     // fragment lane mapping (16x16x32)
  f32x4 acc[4][4] = {};
  const short* A  = (const short*)WoT;  // rows indexed by n
  const short* Bp = (const short*)h2g;  // rows indexed by m
#pragma unroll
  for (int kk = 0; kk < 4; ++kk){
    int ko = kk*32 + lk;
    short8 av[4], bv[4];
#pragma unroll
    for (int i = 0; i < 4; ++i) av[i] = *(const short8*)(A  + (size_t)(n0 + i*16 + lr)*128 + ko);
#pragma unroll
    for (int i = 0; i < 4; ++i) bv[i] = *(const short8*)(Bp + (size_t)(m0 + i*16 + lr)*128 + ko);
#pragma unroll
    for (int fm = 0; fm < 4; ++fm)
#pragma unroll
      for (int fn = 0; fn < 4; ++fn)
        acc[fm][fn] = __builtin_amdgcn_mfma_f32_16x16x32_bf16(av[fn], bv[fm], acc[fm][fn], 0, 0, 0);
  }
  // D layout: col(lane&15) = m index, row((lane>>4)*4+reg) = n index (contiguous)
  int nb_ = (l >> 4)*4;
#pragma unroll
  for (int fn = 0; fn < 4; ++fn){
    f32x4 bia = *(const f32x4*)(bo + n0 + fn*16 + nb_);
#pragma unroll
    for (int fm = 0; fm < 4; ++fm){
      size_t row = (size_t)(m0 + fm*16 + lr)*4096;
      __builtin_nontemporal_store(acc[fm][fn] + bia, (f32x4*)(out + row + n0 + fn*16 + nb_));
    }
  }
}

extern "C" void kernel_launch(void* const* d_in, const int* in_sizes, int n_in,
                              void* d_out, int out_size, void* d_ws, size_t ws_size,
                              hipStream_t stream)
{
  const float* enc = (const float*)d_in[0];
  const float* Wx  = (const float*)d_in[1];
  const float* Wh  = (const float*)d_in[2];
  const float* bh  = (const float*)d_in[3];
  const float* W1  = (const float*)d_in[4];
  const float* b1  = (const float*)d_in[5];
  const float* g1  = (const float*)d_in[6];
  const float* be1 = (const float*)d_in[7];
  const float* W2  = (const float*)d_in[8];
  const float* b2  = (const float*)d_in[9];
  const float* g2  = (const float*)d_in[10];
  const float* be2 = (const float*)d_in[11];
  const float* Wo  = (const float*)d_in[12];
  const float* bo  = (const float*)d_in[13];
  float* out = (float*)d_out;

  const size_t xg_bytes = (size_t)16384*256*4;   // 16 MiB
  const size_t hs_bytes = (size_t)16384*64*4;    //  4 MiB
  const size_t h2_bytes = (size_t)16384*128*2;   //  4 MiB (bf16)
  const size_t wt_bytes = (size_t)4096*128*2;    //  1 MiB (bf16)
  char* ws = (char*)d_ws;
  float *xg, *hs; __hip_bfloat16 *h2g, *WoT;
  if (ws_size >= xg_bytes + hs_bytes + h2_bytes + wt_bytes){
    xg  = (float*)ws;
    hs  = (float*)(ws + xg_bytes);
    h2g = (__hip_bfloat16*)(ws + xg_bytes + hs_bytes);
    WoT = (__hip_bfloat16*)(ws + xg_bytes + hs_bytes + h2_bytes);
  } else {
    // scratch-starved fallback: xg/hs live in d_out (dead before k_out overwrites it)
    xg  = (float*)d_out;
    hs  = (float*)((char*)d_out + xg_bytes);
    h2g = (__hip_bfloat16*)ws;
    WoT = (__hip_bfloat16*)(ws + h2_bytes);
  }

  k_xg  <<<256,  256, 0, stream>>>(enc, Wx, bh, xg);
  k_wot <<<64,   256, 0, stream>>>(Wo, WoT);
  k_lstm<<<32,   256, 0, stream>>>(xg, Wh, hs);
  k_mlp <<<256,  256, 0, stream>>>(hs, W1, b1, g1, be1, W2, b2, g2, be2, h2g);
  k_out <<<4096, 256, 0, stream>>>(h2g, WoT, bo, out);
}

// Round 4
// 425.986 us; speedup vs baseline: 1.9360x; 1.1067x over previous
//
#include <hip/hip_runtime.h>
#include <hip/hip_bf16.h>

// Sizes (hard-coded from reference): B=32, T=512, D=64, H=64, S=4096, 4H=256, 2H=128
#define T_ 512

typedef __attribute__((ext_vector_type(8))) short short8;
typedef __attribute__((ext_vector_type(4))) float f32x4;

__device__ __forceinline__ float fast_rcp(float x){ return __builtin_amdgcn_rcpf(x); }
// Clamp-free: exp->inf saturates cleanly through rcp (sigmoid->0/1, tanh->+-1)
__device__ __forceinline__ float sigmoid_f(float x){
  return fast_rcp(1.f + __expf(-x));
}
__device__ __forceinline__ float tanh_f(float x){
  return fmaf(2.f, fast_rcp(1.f + __expf(-2.f*x)), -1.f);
}
__device__ __forceinline__ float gelu_f(float x){
  float u = 0.7978845608028654f*(x + 0.044715f*x*x*x);
  return 0.5f*x*(1.f + tanh_f(u));
}
__device__ __forceinline__ float readlane_f(float v, int lane){
  return __int_as_float(__builtin_amdgcn_readlane(__float_as_int(v), lane));
}

// ---------------- Kernel 1: xg = enc @ Wx + bh (bias folded) ----------------
// enc [16384,64], Wx [64,256] -> xg [16384,256] fp32
__global__ __launch_bounds__(256, 1) void k_xg(const float* __restrict__ enc,
                                               const float* __restrict__ Wx,
                                               const float* __restrict__ bh,
                                               float* __restrict__ xg)
{
  __shared__ __align__(16) float es[64*64];
  int j = threadIdx.x;
  int g = blockIdx.x;                     // 256 blocks, 64 rows each
  const float* encg = enc + (size_t)g*64*64;
  for (int idx = j; idx < 64*64; idx += 256) es[idx] = encg[idx];
  float wx[64];
#pragma unroll
  for (int k = 0; k < 64; ++k) wx[k] = Wx[k*256 + j];   // column j in regs (resident now)
  float bj = bh[j];
  __syncthreads();
  float* xo = xg + (size_t)g*64*256;
  for (int r = 0; r < 64; ++r){
    const float4* e4 = (const float4*)(es + r*64);
    float z0 = bj, z1 = 0.f, z2 = 0.f, z3 = 0.f;
#pragma unroll
    for (int k4 = 0; k4 < 16; ++k4){
      float4 v = e4[k4];
      z0 = fmaf(v.x, wx[4*k4+0], z0);
      z1 = fmaf(v.y, wx[4*k4+1], z1);
      z2 = fmaf(v.z, wx[4*k4+2], z2);
      z3 = fmaf(v.w, wx[4*k4+3], z3);
    }
    xo[r*256 + j] = (z0+z1)+(z2+z3);
  }
}

// ---------------- Kernel 2: persistent LSTM, one WG per batch ----------------
// Wave w computes gate-block w: thread tid owns column j=tid of z.
// z exchanged via double-buffered LDS (1 write + 4 reads per wave per step).
// Every wave computes ALL 64 h's redundantly in-lane (lane k holds h[k]); the
// h@Wh matvec reads h via v_readlane (SGPR operand FMA) -> zero LDS broadcast.
// Exactly one barrier per step. Wh column resident in 64 VGPRs (launch_bounds 1).
__global__ __launch_bounds__(256, 1) void k_lstm(const float* __restrict__ xg,
                                                 const float* __restrict__ Wh,
                                                 float* __restrict__ hs)
{
  __shared__ __align__(16) float zsm[2][256];
  int tid = threadIdx.x;
  int w = tid >> 6, l = tid & 63;
  int j = tid;                          // column of Wh/xg this thread computes
  int b = blockIdx.x;
  float wh[64];
#pragma unroll
  for (int k = 0; k < 64; ++k) wh[k] = Wh[k*256 + j];   // Wh[:,j] in regs
  float c = 0.f;                        // lane l holds unit-l state (replicated per wave)
  const float* xr = xg + (size_t)b*T_*256;
  float* ho = hs + (size_t)b*T_*64;
  float xn0 = xr[1*256 + j];            // 4-deep prefetch: x_{t+1..t+4}
  float xn1 = xr[2*256 + j];
  float xn2 = xr[3*256 + j];
  float xn3 = xr[4*256 + j];
  zsm[0][j] = xr[j];                    // z_0 = x_0 (h_0 = 0, bias folded in xg)
  __syncthreads();

#define LSTM_STEP(tt, xn)                                                     \
  {                                                                           \
    const float* zb = zsm[(tt) & 1];                                          \
    float zi = zb[l], zf = zb[64+l], zg_ = zb[128+l], zo = zb[192+l];         \
    c = sigmoid_f(zf)*c + sigmoid_f(zi)*tanh_f(zg_);                          \
    float h = sigmoid_f(zo)*tanh_f(c);                                        \
    if (w == 0) ho[(size_t)(tt)*64 + l] = h;                                  \
    if ((tt) + 1 < T_){                                                       \
      float z0 = (xn), z1 = 0.f, z2 = 0.f, z3 = 0.f;                          \
      if ((tt) + 5 < T_) (xn) = xr[(size_t)((tt)+5)*256 + j];                 \
      _Pragma("unroll")                                                       \
      for (int k = 0; k < 64; k += 4){                                        \
        z0 = fmaf(readlane_f(h, k+0), wh[k+0], z0);                           \
        z1 = fmaf(readlane_f(h, k+1), wh[k+1], z1);                           \
        z2 = fmaf(readlane_f(h, k+2), wh[k+2], z2);                           \
        z3 = fmaf(readlane_f(h, k+3), wh[k+3], z3);                           \
      }                                                                       \
      zsm[((tt)+1) & 1][j] = (z0+z1)+(z2+z3);                                 \
    }                                                                         \
    __syncthreads();                                                          \
  }

  for (int t = 0; t < T_; t += 4){
    LSTM_STEP(t,   xn0);
    LSTM_STEP(t+1, xn1);
    LSTM_STEP(t+2, xn2);
    LSTM_STEP(t+3, xn3);
  }
#undef LSTM_STEP
}

// ---------------- Kernel 3: fused MLP (LN+gelu twice), writes h2 as bf16 ----
// hs [16384,64] -> h2g [16384,128] bf16
__global__ __launch_bounds__(256, 1) void k_mlp(const float* __restrict__ hs,
    const float* __restrict__ W1, const float* __restrict__ b1,
    const float* __restrict__ g1, const float* __restrict__ be1,
    const float* __restrict__ W2, const float* __restrict__ b2,
    const float* __restrict__ g2, const float* __restrict__ be2,
    __hip_bfloat16* __restrict__ h2g)
{
  __shared__ __align__(16) float xs[2][64];
  __shared__ __align__(16) float vs[2][128];
  __shared__ float red[2][2][2];
  int tid = threadIdx.x;
  int jj = tid & 127, rg = tid >> 7;    // output column, row-group (2 rows per pass)
  int lane = tid & 63;
  int whalf = (tid >> 6) & 1;           // which wave within the row-group
  float w1c[64], w2c[128];
#pragma unroll
  for (int k = 0; k < 64; ++k) w1c[k] = W1[k*128 + jj];   // resident now
#pragma unroll
  for (int k = 0; k < 128; ++k) w2c[k] = W2[k*128 + jj];  // resident now
  float b1j = b1[jj], g1j = g1[jj], be1j = be1[jj];
  float b2j = b2[jj], g2j = g2[jj], be2j = be2[jj];
  int base = blockIdx.x * 64;           // 256 blocks x 64 rows
  for (int p = 0; p < 32; ++p){
    int r = base + p*2 + rg;
    if (whalf == 0) xs[rg][lane] = hs[(size_t)r*64 + lane];
    __syncthreads();                                    // B1: xs ready
    float a0 = b1j, a1 = 0.f;
    const float4* x4 = (const float4*)xs[rg];
#pragma unroll
    for (int k4 = 0; k4 < 16; ++k4){
      float4 v = x4[k4];
      a0 = fmaf(v.x, w1c[4*k4+0], a0);
      a1 = fmaf(v.y, w1c[4*k4+1], a1);
      a0 = fmaf(v.z, w1c[4*k4+2], a0);
      a1 = fmaf(v.w, w1c[4*k4+3], a1);
    }
    float a = a0 + a1;
    float s1 = a, s2 = a*a;
#pragma unroll
    for (int off = 32; off > 0; off >>= 1){
      s1 += __shfl_xor(s1, off, 64);
      s2 += __shfl_xor(s2, off, 64);
    }
    if (lane == 0){ red[rg][whalf][0] = s1; red[rg][whalf][1] = s2; }
    __syncthreads();                                    // B2: red ready
    s1 = red[rg][0][0] + red[rg][1][0];
    s2 = red[rg][0][1] + red[rg][1][1];
    float mean = s1*(1.f/128.f);
    float var  = s2*(1.f/128.f) - mean*mean;
    float rstd = rsqrtf(var + 1e-6f);
    float y = gelu_f((a - mean)*rstd*g1j + be1j);
    vs[rg][jj] = y;
    __syncthreads();                                    // B3: vs ready (also orders red reuse)
    float c0 = b2j, c1 = 0.f;
    const float4* v4 = (const float4*)vs[rg];
#pragma unroll
    for (int k4 = 0; k4 < 32; ++k4){
      float4 v = v4[k4];
      c0 = fmaf(v.x, w2c[4*k4+0], c0);
      c1 = fmaf(v.y, w2c[4*k4+1], c1);
      c0 = fmaf(v.z, w2c[4*k4+2], c0);
      c1 = fmaf(v.w, w2c[4*k4+3], c1);
    }
    float cc = c0 + c1;
    float t1 = cc, t2 = cc*cc;
#pragma unroll
    for (int off = 32; off > 0; off >>= 1){
      t1 += __shfl_xor(t1, off, 64);
      t2 += __shfl_xor(t2, off, 64);
    }
    if (lane == 0){ red[rg][whalf][0] = t1; red[rg][whalf][1] = t2; }
    __syncthreads();                                    // B4: red2 ready
    t1 = red[rg][0][0] + red[rg][1][0];
    t2 = red[rg][0][1] + red[rg][1][1];
    mean = t1*(1.f/128.f);
    var  = t2*(1.f/128.f) - mean*mean;
    rstd = rsqrtf(var + 1e-6f);
    float z = gelu_f((cc - mean)*rstd*g2j + be2j);
    h2g[(size_t)r*128 + jj] = __float2bfloat16(z);
  }
}

// ---------------- Kernel 3.5: Wo fp32 [128,4096] -> WoT bf16 [4096,128] -----
__global__ __launch_bounds__(256, 1) void k_wot(const float* __restrict__ Wo,
                                                __hip_bfloat16* __restrict__ WoT)
{
  __shared__ __hip_bfloat16 tl[64][130];   // pad to dodge write conflicts
  int tid = threadIdx.x;
  int n0 = blockIdx.x * 64;                // 64 blocks of 64 n-columns
  for (int idx = tid; idx < 64*128; idx += 256){
    int k = idx >> 6, nl = idx & 63;       // coalesced read of Wo row k
    tl[nl][k] = __float2bfloat16(Wo[(size_t)k*4096 + n0 + nl]);
  }
  __syncthreads();
  for (int idx = tid; idx < 64*128; idx += 256){
    int nl = idx >> 7, k = idx & 127;      // coalesced write of WoT row
    WoT[(size_t)(n0 + nl)*128 + k] = tl[nl][k];
  }
}

// ---------------- Kernel 4: out = h2 @ Wo + bo via bf16 MFMA ----------------
// 128x128 block tile (4 waves 2x2, 4x4 fragments each).
// A=WoT (rows=n), B=h2g (rows=m) so D's reg axis runs along n -> float4 stores.
__global__ __launch_bounds__(256, 1) void k_out(const __hip_bfloat16* __restrict__ h2g,
                                                const __hip_bfloat16* __restrict__ WoT,
                                                const float* __restrict__ bo,
                                                float* __restrict__ out)
{
  int bid = blockIdx.x;                 // 4096 = 128 Mb x 32 Nb (Nb inner: share m-panel)
  int Mb = bid >> 5, Nb = bid & 31;
  int tid = threadIdx.x;
  int w = tid >> 6, l = tid & 63;
  int wm = w >> 1, wn = w & 1;          // 2x2 waves -> 128(m) x 128(n)
  int m0 = Mb*128 + wm*64, n0 = Nb*128 + wn*64;
  int lr = l & 15, lk = (l >> 4)*8;     // fragment lane mapping (16x16x32)
  f32x4 acc[4][4] = {};
  const short* A  = (const short*)WoT;  // rows indexed by n
  const short* Bp = (const short*)h2g;  // rows indexed by m
#pragma unroll
  for (int kk = 0; kk < 4; ++kk){
    int ko = kk*32 + lk;
    short8 av[4], bv[4];
#pragma unroll
    for (int i = 0; i < 4; ++i) av[i] = *(const short8*)(A  + (size_t)(n0 + i*16 + lr)*128 + ko);
#pragma unroll
    for (int i = 0; i < 4; ++i) bv[i] = *(const short8*)(Bp + (size_t)(m0 + i*16 + lr)*128 + ko);
#pragma unroll
    for (int fm = 0; fm < 4; ++fm)
#pragma unroll
      for (int fn = 0; fn < 4; ++fn)
        acc[fm][fn] = __builtin_amdgcn_mfma_f32_16x16x32_bf16(av[fn], bv[fm], acc[fm][fn], 0, 0, 0);
  }
  // D layout: col(lane&15) = m index, row((lane>>4)*4+reg) = n index (contiguous)
  int nb_ = (l >> 4)*4;
#pragma unroll
  for (int fn = 0; fn < 4; ++fn){
    f32x4 bia = *(const f32x4*)(bo + n0 + fn*16 + nb_);
#pragma unroll
    for (int fm = 0; fm < 4; ++fm){
      size_t row = (size_t)(m0 + fm*16 + lr)*4096;
      __builtin_nontemporal_store(acc[fm][fn] + bia, (f32x4*)(out + row + n0 + fn*16 + nb_));
    }
  }
}

extern "C" void kernel_launch(void* const* d_in, const int* in_sizes, int n_in,
                              void* d_out, int out_size, void* d_ws, size_t ws_size,
                              hipStream_t stream)
{
  const float* enc = (const float*)d_in[0];
  const float* Wx  = (const float*)d_in[1];
  const float* Wh  = (const float*)d_in[2];
  const float* bh  = (const float*)d_in[3];
  const float* W1  = (const float*)d_in[4];
  const float* b1  = (const float*)d_in[5];
  const float* g1  = (const float*)d_in[6];
  const float* be1 = (const float*)d_in[7];
  const float* W2  = (const float*)d_in[8];
  const float* b2  = (const float*)d_in[9];
  const float* g2  = (const float*)d_in[10];
  const float* be2 = (const float*)d_in[11];
  const float* Wo  = (const float*)d_in[12];
  const float* bo  = (const float*)d_in[13];
  float* out = (float*)d_out;

  const size_t xg_bytes = (size_t)16384*256*4;   // 16 MiB
  const size_t hs_bytes = (size_t)16384*64*4;    //  4 MiB
  const size_t h2_bytes = (size_t)16384*128*2;   //  4 MiB (bf16)
  const size_t wt_bytes = (size_t)4096*128*2;    //  1 MiB (bf16)
  char* ws = (char*)d_ws;
  float *xg, *hs; __hip_bfloat16 *h2g, *WoT;
  if (ws_size >= xg_bytes + hs_bytes + h2_bytes + wt_bytes){
    xg  = (float*)ws;
    hs  = (float*)(ws + xg_bytes);
    h2g = (__hip_bfloat16*)(ws + xg_bytes + hs_bytes);
    WoT = (__hip_bfloat16*)(ws + xg_bytes + hs_bytes + h2_bytes);
  } else {
    // scratch-starved fallback: xg/hs live in d_out (dead before k_out overwrites it)
    xg  = (float*)d_out;
    hs  = (float*)((char*)d_out + xg_bytes);
    h2g = (__hip_bfloat16*)ws;
    WoT = (__hip_bfloat16*)(ws + h2_bytes);
  }

  k_xg  <<<256,  256, 0, stream>>>(enc, Wx, bh, xg);
  k_wot <<<64,   256, 0, stream>>>(Wo, WoT);
  k_lstm<<<32,   256, 0, stream>>>(xg, Wh, hs);
  k_mlp <<<256,  256, 0, stream>>>(hs, W1, b1, g1, be1, W2, b2, g2, be2, h2g);
  k_out <<<4096, 256, 0, stream>>>(h2g, WoT, bo, out);
}